// Round 1
// baseline (1006.560 us; speedup 1.0000x reference)
//
#include <hip/hip_runtime.h>

// GradientCurvatureAttention: fused depthwise-conv + curvature + channel-softmax + scale.
// x: [B=16, C=128, H=128, W=128] fp32, NCHW. out: same shape.
// One thread per pixel, channel loop fully unrolled with s[128] held in VGPRs.

#define GCA_B 16
#define GCA_C 128
#define GCA_H 128
#define GCA_W 128

__global__ __launch_bounds__(256) void gca_fused_kernel(const float* __restrict__ x,
                                                        float* __restrict__ out) {
    const int w = blockIdx.x * 64 + threadIdx.x;   // 0..127
    const int h = blockIdx.y * 4 + threadIdx.y;    // 0..127
    const int b = blockIdx.z;                      // 0..15

    // Clamped neighbor coords + zero masks for padding=1 (conv pads with 0).
    const int hm = (h > 0) ? h - 1 : 0;
    const int hp = (h < GCA_H - 1) ? h + 1 : GCA_H - 1;
    const int wm = (w > 0) ? w - 1 : 0;
    const int wp = (w < GCA_W - 1) ? w + 1 : GCA_W - 1;
    const float mh0 = (h > 0) ? 1.f : 0.f;
    const float mh2 = (h < GCA_H - 1) ? 1.f : 0.f;
    const float mw0 = (w > 0) ? 1.f : 0.f;
    const float mw2 = (w < GCA_W - 1) ? 1.f : 0.f;
    const float m00 = mh0 * mw0, m01 = mh0, m02 = mh0 * mw2;
    const float m10 = mw0,                  m12 = mw2;
    const float m20 = mh2 * mw0, m21 = mh2, m22 = mh2 * mw2;

    const size_t plane = (size_t)GCA_H * GCA_W;
    const float* base = x + (size_t)b * GCA_C * plane;
    float* obase      = out + (size_t)b * GCA_C * plane;

    const int o00 = hm * GCA_W + wm, o01 = hm * GCA_W + w, o02 = hm * GCA_W + wp;
    const int o10 = h  * GCA_W + wm, o11 = h  * GCA_W + w, o12 = h  * GCA_W + wp;
    const int o20 = hp * GCA_W + wm, o21 = hp * GCA_W + w, o22 = hp * GCA_W + wp;

    float s[GCA_C];
    float smax = -3.0e38f;

    // Pass 1: per-channel conv + curvature score, track running max.
    #pragma unroll
    for (int c = 0; c < GCA_C; ++c) {
        const float* p = base + (size_t)c * plane;
        const float t00 = p[o00] * m00, t01 = p[o01] * m01, t02 = p[o02] * m02;
        const float t10 = p[o10] * m10, t11 = p[o11],       t12 = p[o12] * m12;
        const float t20 = p[o20] * m20, t21 = p[o21] * m21, t22 = p[o22] * m22;

        const float r0p = t00 + 2.f * t01 + t02;
        const float r1p = t10 + 2.f * t11 + t12;
        const float r2p = t20 + 2.f * t21 + t22;
        const float r0m = t00 - t02;
        const float r1m = t10 - t12;
        const float r2m = t20 - t22;

        const float Gx  = r0m + 2.f * r1m + r2m;                 // SOBEL_X (corr)
        const float Gy  = r0p - r2p;                              // SOBEL_Y
        const float Ixx = (r0p - 4.f * t01) + 2.f * (r1p - 4.f * t11) + (r2p - 4.f * t21);
        const float Iyy = r0p - 2.f * r1p + r2p;                  // K_YY
        const float Ixy = r2m - r0m;                              // K_XY

        const float gx2 = Gx * Gx;
        const float gy2 = Gy * Gy;
        const float g2e = gx2 + gy2 + 1e-6f;
        const float r   = rsqrtf(g2e);            // 1/sqrt(g2e)
        const float gm  = g2e * r;                // sqrt(g2e)
        const float num = gx2 * Iyy - 2.f * (Gx * Gy) * Ixy + gy2 * Ixx;
        const float curv = num * (r * r * r);     // num / g2e^1.5
        const float sc  = gm + curv;
        s[c] = sc;
        smax = fmaxf(smax, sc);
    }

    // Pass 2: exponentiate + sum (overwrite s[c] with exp value).
    float ssum = 0.f;
    #pragma unroll
    for (int c = 0; c < GCA_C; ++c) {
        const float e = __expf(s[c] - smax);
        s[c] = e;
        ssum += e;
    }
    const float inv = 1.f / ssum;

    // Pass 3: out = (softmax + 1) * x = fma(e*inv, x, x). Center tap re-read (cache-hot).
    #pragma unroll
    for (int c = 0; c < GCA_C; ++c) {
        const float xc = base[(size_t)c * plane + o11];
        obase[(size_t)c * plane + o11] = fmaf(s[c] * inv, xc, xc);
    }
}

extern "C" void kernel_launch(void* const* d_in, const int* in_sizes, int n_in,
                              void* d_out, int out_size, void* d_ws, size_t ws_size,
                              hipStream_t stream) {
    (void)in_sizes; (void)n_in; (void)d_ws; (void)ws_size; (void)out_size;
    const float* x = (const float*)d_in[0];
    float* out = (float*)d_out;
    dim3 block(64, 4, 1);
    dim3 grid(GCA_W / 64, GCA_H / 4, GCA_B);
    gca_fused_kernel<<<grid, block, 0, stream>>>(x, out);
}

// Round 2
// 150.683 us; speedup vs baseline: 6.6800x; 6.6800x over previous
//
#include <hip/hip_runtime.h>

// GradientCurvatureAttention: fused depthwise-conv + curvature + channel-softmax + scale.
// x: [B=16, C=128, H=128, W=128] fp32, NCHW. out: same shape.
//
// Round 2: fix the register spill of round 1. Channels are split across the
// block's 8 waves (16 channels per wave, s[16]+xc[16] in VGPRs); the channel
// softmax (max, sum) is reduced across waves via two small LDS arrays.

#define GCA_B 16
#define GCA_C 128
#define GCA_H 128
#define GCA_W 128
#define CGRP  8            // channel groups (blockDim.y)
#define CPW   (GCA_C/CGRP) // 16 channels per wave

__global__ __launch_bounds__(512) void gca_fused2(const float* __restrict__ x,
                                                  float* __restrict__ out) {
    const int tx = threadIdx.x;                 // 0..63 : w within 64-chunk
    const int ty = threadIdx.y;                 // 0..7  : channel group
    const int w  = blockIdx.x * 64 + tx;        // 0..127
    const int h  = blockIdx.y;                  // 0..127
    const int b  = blockIdx.z;                  // 0..15
    const int c0 = ty * CPW;

    // Clamped neighbor coords + zero masks for padding=1 (conv pads with 0).
    const int hm = (h > 0) ? h - 1 : 0;
    const int hp = (h < GCA_H - 1) ? h + 1 : GCA_H - 1;
    const int wm = (w > 0) ? w - 1 : 0;
    const int wp = (w < GCA_W - 1) ? w + 1 : GCA_W - 1;
    const float mh0 = (h > 0) ? 1.f : 0.f;
    const float mh2 = (h < GCA_H - 1) ? 1.f : 0.f;
    const float mw0 = (w > 0) ? 1.f : 0.f;
    const float mw2 = (w < GCA_W - 1) ? 1.f : 0.f;
    const float m00 = mh0 * mw0, m01 = mh0, m02 = mh0 * mw2;
    const float m10 = mw0,                  m12 = mw2;
    const float m20 = mh2 * mw0, m21 = mh2, m22 = mh2 * mw2;

    const size_t plane = (size_t)GCA_H * GCA_W;
    const float* base = x   + ((size_t)b * GCA_C + c0) * plane;
    float* obase      = out + ((size_t)b * GCA_C + c0) * plane;

    const int o00 = hm * GCA_W + wm, o01 = hm * GCA_W + w, o02 = hm * GCA_W + wp;
    const int o10 = h  * GCA_W + wm, o11 = h  * GCA_W + w, o12 = h  * GCA_W + wp;
    const int o20 = hp * GCA_W + wm, o21 = hp * GCA_W + w, o22 = hp * GCA_W + wp;

    float s[CPW];   // score, then exp(score - gmax)
    float xc[CPW];  // center tap, kept for the epilogue
    float lmax = -3.0e38f;

    // Pass 1: per-channel conv + curvature score for this wave's 16 channels.
    #pragma unroll
    for (int i = 0; i < CPW; ++i) {
        const float* p = base + (size_t)i * plane;
        const float t11 = p[o11];
        const float t00 = p[o00] * m00, t01 = p[o01] * m01, t02 = p[o02] * m02;
        const float t10 = p[o10] * m10,                     t12 = p[o12] * m12;
        const float t20 = p[o20] * m20, t21 = p[o21] * m21, t22 = p[o22] * m22;

        const float r0p = t00 + 2.f * t01 + t02;
        const float r1p = t10 + 2.f * t11 + t12;
        const float r2p = t20 + 2.f * t21 + t22;
        const float r0m = t00 - t02;
        const float r1m = t10 - t12;
        const float r2m = t20 - t22;

        const float Gx  = r0m + 2.f * r1m + r2m;                  // SOBEL_X
        const float Gy  = r0p - r2p;                              // SOBEL_Y
        const float Ixx = (r0p - 4.f * t01) + 2.f * (r1p - 4.f * t11) + (r2p - 4.f * t21);
        const float Iyy = r0p - 2.f * r1p + r2p;                  // K_YY
        const float Ixy = r2m - r0m;                              // K_XY

        const float gx2 = Gx * Gx;
        const float gy2 = Gy * Gy;
        const float g2e = gx2 + gy2 + 1e-6f;
        const float r   = rsqrtf(g2e);            // 1/sqrt(g2e)
        const float gm  = g2e * r;                // sqrt(g2e)
        const float num = gx2 * Iyy - 2.f * (Gx * Gy) * Ixy + gy2 * Ixx;
        const float curv = num * (r * r * r);     // num / g2e^1.5
        const float sc  = gm + curv;
        s[i]  = sc;
        xc[i] = t11;
        lmax  = fmaxf(lmax, sc);
    }

    // Cross-wave softmax reduction (per pixel, over the 8 channel groups).
    __shared__ float redmax[CGRP][64];
    __shared__ float redsum[CGRP][64];

    redmax[ty][tx] = lmax;
    __syncthreads();
    float gmax = redmax[0][tx];
    #pragma unroll
    for (int g = 1; g < CGRP; ++g) gmax = fmaxf(gmax, redmax[g][tx]);

    float lsum = 0.f;
    #pragma unroll
    for (int i = 0; i < CPW; ++i) {
        const float e = __expf(s[i] - gmax);
        s[i] = e;
        lsum += e;
    }
    redsum[ty][tx] = lsum;
    __syncthreads();
    float tot = redsum[0][tx];
    #pragma unroll
    for (int g = 1; g < CGRP; ++g) tot += redsum[g][tx];
    const float inv = 1.f / tot;

    // Epilogue: out = (softmax + 1) * x = fma(e*inv, xc, xc).
    #pragma unroll
    for (int i = 0; i < CPW; ++i) {
        obase[(size_t)i * plane + o11] = fmaf(s[i] * inv, xc[i], xc[i]);
    }
}

extern "C" void kernel_launch(void* const* d_in, const int* in_sizes, int n_in,
                              void* d_out, int out_size, void* d_ws, size_t ws_size,
                              hipStream_t stream) {
    (void)in_sizes; (void)n_in; (void)d_ws; (void)ws_size; (void)out_size;
    const float* x = (const float*)d_in[0];
    float* out = (float*)d_out;
    dim3 block(64, CGRP, 1);
    dim3 grid(GCA_W / 64, GCA_H, GCA_B);
    gca_fused2<<<grid, block, 0, stream>>>(x, out);
}

// Round 3
// 114.958 us; speedup vs baseline: 8.7559x; 1.3108x over previous
//
#include <hip/hip_runtime.h>

// GradientCurvatureAttention: fused depthwise-conv + curvature + channel-softmax + scale.
// x: [B=16, C=128, H=128, W=128] fp32, NCHW. out: same shape.
//
// Round 3: occupancy + locality.
//  - 16 channel-groups x 8 channels (block = 1024 thr); __launch_bounds__(1024,8)
//    caps VGPR at 64 so TWO blocks (32 waves) co-reside per CU.
//  - XCD-aware 1D grid swizzle: consecutive h-rows land on the same XCD so the
//    h-1/h/h+1 row re-reads hit that XCD's L2.

#define GCA_B 16
#define GCA_C 128
#define GCA_H 128
#define GCA_W 128
#define CGRP  16           // channel groups (blockDim.y, one wave each)
#define CPW   (GCA_C/CGRP) // 8 channels per wave

__global__ __launch_bounds__(1024, 8) void gca_fused3(const float* __restrict__ x,
                                                      float* __restrict__ out) {
    const int tx = threadIdx.x;                 // 0..63 : w within 64-chunk
    const int ty = threadIdx.y;                 // 0..15 : channel group

    // XCD swizzle: nwg = 4096, 8 XCDs, 512 consecutive ids per XCD.
    // id layout: (b, wc, h) with h minor -> ids on one XCD are contiguous h-runs.
    const int id  = blockIdx.x;
    const int swz = ((id & 7) << 9) | (id >> 3);
    const int h   = swz & 127;
    const int t2  = swz >> 7;
    const int wc  = t2 & 1;
    const int b   = t2 >> 1;

    const int w  = wc * 64 + tx;                // 0..127
    const int c0 = ty * CPW;

    // Clamped neighbor coords + zero masks for padding=1 (conv pads with 0).
    const int hm = (h > 0) ? h - 1 : 0;
    const int hp = (h < GCA_H - 1) ? h + 1 : GCA_H - 1;
    const int wm = (w > 0) ? w - 1 : 0;
    const int wp = (w < GCA_W - 1) ? w + 1 : GCA_W - 1;
    const float mh0 = (h > 0) ? 1.f : 0.f;
    const float mh2 = (h < GCA_H - 1) ? 1.f : 0.f;
    const float mw0 = (w > 0) ? 1.f : 0.f;
    const float mw2 = (w < GCA_W - 1) ? 1.f : 0.f;
    const float m00 = mh0 * mw0, m01 = mh0, m02 = mh0 * mw2;
    const float m10 = mw0,                  m12 = mw2;
    const float m20 = mh2 * mw0, m21 = mh2, m22 = mh2 * mw2;

    const size_t plane = (size_t)GCA_H * GCA_W;
    const float* base = x   + ((size_t)b * GCA_C + c0) * plane;
    float* obase      = out + ((size_t)b * GCA_C + c0) * plane;

    const int o00 = hm * GCA_W + wm, o01 = hm * GCA_W + w, o02 = hm * GCA_W + wp;
    const int o10 = h  * GCA_W + wm, o11 = h  * GCA_W + w, o12 = h  * GCA_W + wp;
    const int o20 = hp * GCA_W + wm, o21 = hp * GCA_W + w, o22 = hp * GCA_W + wp;

    float s[CPW];   // score, then exp(score - gmax)
    float xc[CPW];  // center tap, kept for the epilogue
    float lmax = -3.0e38f;

    // Pass 1: per-channel conv + curvature score for this wave's 8 channels.
    #pragma unroll
    for (int i = 0; i < CPW; ++i) {
        const float* p = base + (size_t)i * plane;
        const float t11 = p[o11];
        const float t00 = p[o00] * m00, t01 = p[o01] * m01, t02 = p[o02] * m02;
        const float t10 = p[o10] * m10,                     t12 = p[o12] * m12;
        const float t20 = p[o20] * m20, t21 = p[o21] * m21, t22 = p[o22] * m22;

        const float r0p = t00 + 2.f * t01 + t02;
        const float r1p = t10 + 2.f * t11 + t12;
        const float r2p = t20 + 2.f * t21 + t22;
        const float r0m = t00 - t02;
        const float r1m = t10 - t12;
        const float r2m = t20 - t22;

        const float Gx  = r0m + 2.f * r1m + r2m;                  // SOBEL_X
        const float Gy  = r0p - r2p;                              // SOBEL_Y
        const float Ixx = (r0p - 4.f * t01) + 2.f * (r1p - 4.f * t11) + (r2p - 4.f * t21);
        const float Iyy = r0p - 2.f * r1p + r2p;                  // K_YY
        const float Ixy = r2m - r0m;                              // K_XY

        const float gx2 = Gx * Gx;
        const float gy2 = Gy * Gy;
        const float g2e = gx2 + gy2 + 1e-6f;
        const float r   = rsqrtf(g2e);            // 1/sqrt(g2e)
        const float gm  = g2e * r;                // sqrt(g2e)
        const float num = gx2 * Iyy - 2.f * (Gx * Gy) * Ixy + gy2 * Ixx;
        const float curv = num * (r * r * r);     // num / g2e^1.5
        const float sc  = gm + curv;
        s[i]  = sc;
        xc[i] = t11;
        lmax  = fmaxf(lmax, sc);
    }

    // Cross-wave softmax reduction (per pixel, over the 16 channel groups).
    __shared__ float redmax[CGRP][64];
    __shared__ float redsum[CGRP][64];

    redmax[ty][tx] = lmax;
    __syncthreads();
    float gmax = redmax[0][tx];
    #pragma unroll
    for (int g = 1; g < CGRP; ++g) gmax = fmaxf(gmax, redmax[g][tx]);

    float lsum = 0.f;
    #pragma unroll
    for (int i = 0; i < CPW; ++i) {
        const float e = __expf(s[i] - gmax);
        s[i] = e;
        lsum += e;
    }
    redsum[ty][tx] = lsum;
    __syncthreads();
    float tot = redsum[0][tx];
    #pragma unroll
    for (int g = 1; g < CGRP; ++g) tot += redsum[g][tx];
    const float inv = 1.f / tot;

    // Epilogue: out = (softmax + 1) * x = fma(e*inv, xc, xc).
    #pragma unroll
    for (int i = 0; i < CPW; ++i) {
        obase[(size_t)i * plane + o11] = fmaf(s[i] * inv, xc[i], xc[i]);
    }
}

extern "C" void kernel_launch(void* const* d_in, const int* in_sizes, int n_in,
                              void* d_out, int out_size, void* d_ws, size_t ws_size,
                              hipStream_t stream) {
    (void)in_sizes; (void)n_in; (void)d_ws; (void)ws_size; (void)out_size;
    const float* x = (const float*)d_in[0];
    float* out = (float*)d_out;
    dim3 block(64, CGRP, 1);
    dim3 grid((GCA_W / 64) * GCA_H * GCA_B, 1, 1);  // 4096 blocks, swizzled in-kernel
    gca_fused3<<<grid, block, 0, stream>>>(x, out);
}

// Round 4
// 96.760 us; speedup vs baseline: 10.4027x; 1.1881x over previous
//
#include <hip/hip_runtime.h>

// GradientCurvatureAttention: fused depthwise-conv + curvature + channel-softmax + scale.
// x: [B=16, C=128, H=128, W=128] fp32, NCHW. out: same shape.
//
// Round 4: vectorize. 2 pixels/thread (float2 loads/stores), halo columns via
// wave shuffles, no xc[] cache (center row reloaded from L2 in epilogue), so
// per-thread state is just sA[8]+sB[8] -> no spill, 2 blocks/CU possible.

#define GCA_B 16
#define GCA_C 128
#define GCA_H 128
#define GCA_W 128
#define CGRP  16           // channel groups (blockDim.y, one wave each)
#define CPW   (GCA_C/CGRP) // 8 channels per wave

__device__ __forceinline__ float gca_score(float rp0, float rp1, float rp2,
                                           float rm0, float rm1, float rm2,
                                           float colc) {
    const float Gx  = rm0 + 2.f * rm1 + rm2;                 // SOBEL_X
    const float Gy  = rp0 - rp2;                             // SOBEL_Y
    const float Iyy = rp0 - 2.f * rp1 + rp2;                 // K_YY
    const float Ixy = rm2 - rm0;                             // K_XY
    const float Ixx = (rp0 + 2.f * rp1 + rp2) - 4.f * colc;  // K_XX
    const float gx2 = Gx * Gx, gy2 = Gy * Gy;
    const float g2e = gx2 + gy2 + 1e-6f;
    const float r   = rsqrtf(g2e);
    const float gm  = g2e * r;                               // sqrt(g2e)
    const float num = gx2 * Iyy - 2.f * (Gx * Gy) * Ixy + gy2 * Ixx;
    return gm + num * (r * r * r);                           // grad_mag + curvature
}

__global__ __launch_bounds__(1024, 4) void gca_fused4(const float* __restrict__ x,
                                                      float* __restrict__ out) {
    const int tx = threadIdx.x;                 // 0..63 : pixel pair, w0 = 2*tx
    const int ty = threadIdx.y;                 // 0..15 : channel group

    // XCD swizzle: 2048 blocks (= B*H, h minor), 256 consecutive ids per XCD
    // so h-neighbor rows land on the same XCD's L2.
    const int id  = blockIdx.x;
    const int swz = ((id & 7) << 8) | (id >> 3);
    const int h   = swz & 127;
    const int b   = swz >> 7;

    const int w0 = tx * 2;
    const int c0 = ty * CPW;

    const int hm = (h > 0) ? h - 1 : 0;
    const int hp = (h < GCA_H - 1) ? h + 1 : GCA_H - 1;
    const float mh0 = (h > 0) ? 1.f : 0.f;
    const float mh2 = (h < GCA_H - 1) ? 1.f : 0.f;
    const float mwA = (tx > 0) ? 1.f : 0.f;   // pixel A's left col exists
    const float mwB = (tx < 63) ? 1.f : 0.f;  // pixel B's right col exists
    const float mA0 = mwA * mh0, mB0 = mwB * mh0;
    const float mA2 = mwA * mh2, mB2 = mwB * mh2;

    const size_t plane = (size_t)GCA_H * GCA_W;
    const float* base = x   + ((size_t)b * GCA_C + c0) * plane;
    float* obase      = out + ((size_t)b * GCA_C + c0) * plane;

    const int r0off = hm * GCA_W + w0;
    const int r1off = h  * GCA_W + w0;
    const int r2off = hp * GCA_W + w0;

    float sA[CPW], sB[CPW];
    float lmaxA = -3.0e38f, lmaxB = -3.0e38f;

    // Pass 1: conv + curvature scores for 2 pixels x 8 channels.
    #pragma unroll
    for (int i = 0; i < CPW; ++i) {
        const float* p = base + (size_t)i * plane;
        const float2 v0 = *(const float2*)(p + r0off);
        const float2 v1 = *(const float2*)(p + r1off);
        const float2 v2 = *(const float2*)(p + r2off);
        const float L0 = __shfl_up(v0.y, 1), R0 = __shfl_down(v0.x, 1);
        const float L1 = __shfl_up(v1.y, 1), R1 = __shfl_down(v1.x, 1);
        const float L2 = __shfl_up(v2.y, 1), R2 = __shfl_down(v2.x, 1);

        // masked column values: a=w0-1, b=w0, c=w0+1, d=w0+2 per row
        const float a0 = L0 * mA0, b0 = v0.x * mh0, c0v = v0.y * mh0, d0 = R0 * mB0;
        const float a1 = L1 * mwA, b1 = v1.x,       c1v = v1.y,       d1 = R1 * mwB;
        const float a2 = L2 * mA2, b2 = v2.x * mh2, c2v = v2.y * mh2, d2 = R2 * mB2;

        const float scA = gca_score(a0 + 2.f * b0 + c0v,
                                    a1 + 2.f * b1 + c1v,
                                    a2 + 2.f * b2 + c2v,
                                    a0 - c0v, a1 - c1v, a2 - c2v,
                                    b0 + 2.f * b1 + b2);
        const float scB = gca_score(b0 + 2.f * c0v + d0,
                                    b1 + 2.f * c1v + d1,
                                    b2 + 2.f * c2v + d2,
                                    b0 - d0, b1 - d1, b2 - d2,
                                    c0v + 2.f * c1v + c2v);
        sA[i] = scA; sB[i] = scB;
        lmaxA = fmaxf(lmaxA, scA);
        lmaxB = fmaxf(lmaxB, scB);
    }

    // Cross-wave softmax reduction (per pixel, over the 16 channel groups).
    __shared__ float2 redmax[CGRP][64];
    __shared__ float2 redsum[CGRP][64];

    redmax[ty][tx] = make_float2(lmaxA, lmaxB);
    __syncthreads();
    float gmaxA = -3.0e38f, gmaxB = -3.0e38f;
    #pragma unroll
    for (int g = 0; g < CGRP; ++g) {
        const float2 m = redmax[g][tx];
        gmaxA = fmaxf(gmaxA, m.x);
        gmaxB = fmaxf(gmaxB, m.y);
    }

    float lsumA = 0.f, lsumB = 0.f;
    #pragma unroll
    for (int i = 0; i < CPW; ++i) {
        const float eA = __expf(sA[i] - gmaxA);
        const float eB = __expf(sB[i] - gmaxB);
        sA[i] = eA; sB[i] = eB;
        lsumA += eA; lsumB += eB;
    }
    redsum[ty][tx] = make_float2(lsumA, lsumB);
    __syncthreads();
    float totA = 0.f, totB = 0.f;
    #pragma unroll
    for (int g = 0; g < CGRP; ++g) {
        const float2 sm = redsum[g][tx];
        totA += sm.x;
        totB += sm.y;
    }
    const float invA = 1.f / totA;
    const float invB = 1.f / totB;

    // Epilogue: out = (softmax + 1) * x; center row reloaded (L2-resident).
    #pragma unroll
    for (int i = 0; i < CPW; ++i) {
        const float2 xv = *(const float2*)(base + (size_t)i * plane + r1off);
        float2 o;
        o.x = fmaf(sA[i] * invA, xv.x, xv.x);
        o.y = fmaf(sB[i] * invB, xv.y, xv.y);
        *(float2*)(obase + (size_t)i * plane + r1off) = o;
    }
}

extern "C" void kernel_launch(void* const* d_in, const int* in_sizes, int n_in,
                              void* d_out, int out_size, void* d_ws, size_t ws_size,
                              hipStream_t stream) {
    (void)in_sizes; (void)n_in; (void)d_ws; (void)ws_size; (void)out_size;
    const float* x = (const float*)d_in[0];
    float* out = (float*)d_out;
    dim3 block(64, CGRP, 1);
    dim3 grid(GCA_B * GCA_H, 1, 1);   // 2048 blocks, swizzled in-kernel
    gca_fused4<<<grid, block, 0, stream>>>(x, out);
}